// Round 14
// baseline (2502.750 us; speedup 1.0000x reference)
//
#include <hip/hip_runtime.h>
#include <hip/hip_bf16.h>

// Problem constants (from reference)
#define N_NODES 50000
#define N_EDGES 150000
#define NODE_IN 64
#define EDGE_IN 16
#define DD 32          // node feature dim
#define EHID 128       // edge-network hidden
#define STEPS 3
#define EPB 64         // edges per fused_msg block: LDS 30208B -> 5 blocks/CU

// Device-verified harness dtypes: float inputs fp32, edge_index int32, output fp32.
__device__ __forceinline__ ushort f2b(float f) {
    __hip_bfloat16 b = __float2bfloat16(f);   // RNE
    return *reinterpret_cast<ushort*>(&b);
}

typedef __bf16 bf16x8 __attribute__((ext_vector_type(8)));
typedef float  f32x4  __attribute__((ext_vector_type(4)));

#define LDA  136   // As leading dim (ushorts)
#define HPAD 36    // Hs leading dim (floats)

// ---------------------------------------------------------------------------
// setup (R12-proven): merged prep + node_init + agg-zero.
// blocks [0,70): weight repack; [70,266): node_init; [266,364): zero agg.
__global__ __launch_bounds__(256) void setup(const float* __restrict__ we2,
                                             const float* __restrict__ we1,
                                             const float* __restrict__ wroot,
                                             const float* __restrict__ wih,
                                             const float* __restrict__ whh,
                                             ushort* __restrict__ we2B,
                                             ushort* __restrict__ we1B,
                                             ushort* __restrict__ wgB,
                                             const float* __restrict__ x,
                                             const float* __restrict__ Wn,
                                             const float* __restrict__ bn,
                                             float* __restrict__ h,
                                             float* __restrict__ agg) {
    __shared__ float Wns[NODE_IN * DD];   // node_init blocks only
    __shared__ float bns[DD];
    int b = blockIdx.x, t = threadIdx.x;

    if (b < 70) {   // ---- prep (R4-proven 16x16 fragment layout) ----
        int i = b * 256 + t;
        if (i < 16384) {
            int l = i & 63, f = i >> 6;           // f = bn*16 + nt*4 + kt
            int kt = f & 3, nt = (f >> 2) & 3, bq = f >> 4;
            int lr = l & 15, lg = l >> 4;
            int n = bq * 64 + nt * 16 + lr;
            int k0 = kt * 32 + lg * 8;
            ushort tmp[8];
#pragma unroll
            for (int j = 0; j < 8; ++j) tmp[j] = f2b(we2[(size_t)(k0 + j) * 1024 + n]);
            *(uint4*)(we2B + (size_t)i * 8) = *(uint4*)tmp;
        } else if (i < 16896) {
            int u = i - 16384;
            int l = u & 63, nt = u >> 6;
            int lr = l & 15, lg = l >> 4;
            int n = nt * 16 + lr;
            ushort tmp[8];
#pragma unroll
            for (int j = 0; j < 8; ++j) {
                int k = lg * 8 + j;
                tmp[j] = (k < EDGE_IN) ? f2b(we1[(size_t)k * EHID + n]) : (ushort)0;
            }
            *(uint4*)(we1B + (size_t)u * 8) = *(uint4*)tmp;
        } else if (i < 17792) {
            int u = i - 16896;
            int l = u & 63;
            int lr = l & 15, lg = l >> 4;
            ushort tmp[8];
            if (u < 128) {            // Wroot [i][o] row-major
                int nt = u >> 6;
#pragma unroll
                for (int j = 0; j < 8; ++j)
                    tmp[j] = f2b(wroot[(size_t)(lg * 8 + j) * DD + nt * 16 + lr]);
            } else if (u < 512) {     // Wih
                int nt = (u - 128) >> 6;
#pragma unroll
                for (int j = 0; j < 8; ++j)
                    tmp[j] = f2b(wih[(size_t)(nt * 16 + lr) * DD + lg * 8 + j]);
            } else {                  // Whh
                int nt = (u - 512) >> 6;
#pragma unroll
                for (int j = 0; j < 8; ++j)
                    tmp[j] = f2b(whh[(size_t)(nt * 16 + lr) * DD + lg * 8 + j]);
            }
            *(uint4*)(wgB + (size_t)u * 8) = *(uint4*)tmp;
        }
    } else if (b < 266) {   // ---- node_init ----
        for (int i = t; i < NODE_IN * DD; i += 256) Wns[i] = Wn[i];
        if (t < DD) bns[t] = bn[t];
        __syncthreads();
        int n = (b - 70) * 256 + t;
        if (n >= N_NODES) return;
        float xr[NODE_IN];
        const float4* xp = (const float4*)(x + (size_t)n * NODE_IN);
#pragma unroll
        for (int q = 0; q < NODE_IN / 4; ++q) *(float4*)&xr[q * 4] = xp[q];
        float out[DD];
#pragma unroll
        for (int o = 0; o < DD; ++o) {
            float s = bns[o];
#pragma unroll
            for (int i = 0; i < NODE_IN; ++i) s += xr[i] * Wns[i * DD + o];
            out[o] = fmaxf(s, 0.f);
        }
        float4* hp = (float4*)(h + (size_t)n * DD);
#pragma unroll
        for (int q = 0; q < DD / 4; ++q) hp[q] = *(float4*)&out[q * 4];
    } else {   // ---- zero agg: blocks [266,364), 16 float4 per thread ----
        size_t total = (size_t)N_NODES * DD;        // 1.6M floats
        size_t base = ((size_t)(b - 266) * 256 + t) * 64;
        float4 z = make_float4(0.f, 0.f, 0.f, 0.f);
#pragma unroll
        for (int q = 0; q < 16; ++q) {
            size_t idx = base + (size_t)q * 4;
            if (idx < total) *(float4*)(agg + idx) = z;
        }
    }
}

// ---------------------------------------------------------------------------
// fused_msg R14: R10 body + bias-in-accumulator identity. acc[nt] is
// initialized to {bv,bv,bv,bv} (MFMA C-in accumulates) so the fold drops
// the per-element +bv (256 VALU adds + 64 LDS reads per wave removed from
// the hot loop). Numerically identical modulo fp32 add order.
__global__ __launch_bounds__(256, 5) void fused_msg(const float* __restrict__ ea,
                                                    const ushort* __restrict__ we1B,
                                                    const float* __restrict__ be1,
                                                    const ushort* __restrict__ we2B,
                                                    const float* __restrict__ be2,
                                                    const int* __restrict__ ei,
                                                    const float* __restrict__ h,
                                                    float* __restrict__ agg) {
    // region = max(As 64x136x2 = 17408B, Hs 9216B + Bs 16384B = 25600B)
    __shared__ __attribute__((aligned(16))) ushort AsHs[12800];      // 25600 B
    __shared__ float b1s[EHID];                                      // 512 B
    __shared__ float be2s[DD * DD];                                  // 4096 B
    float* Hs = (float*)AsHs;            // [64][HPAD] fp32 view (phase B)
    ushort* Bs = AsHs + 4608;            // bytes [9216, 25600): bn weight tile

    int t = threadIdx.x;
    if (t < EHID) b1s[t] = be1[t];
    for (int i = t; i < DD * DD; i += 256) be2s[i] = be2[i];

    int w = t >> 6, l = t & 63;
    int lr = l & 15, lg = l >> 4;
    int e0 = blockIdx.x * EPB;

    // Phase A input fragment straight from global (direct, coalesced)
    bf16x8 afe;
    {
        int e = e0 + w * 16 + lr;
        ushort tmp[8] = {0, 0, 0, 0, 0, 0, 0, 0};
        if (lg < 2 && e < N_EDGES) {
            const float4* p = (const float4*)(ea + (size_t)e * EDGE_IN + lg * 8);
            float4 a = p[0], b = p[1];
            tmp[0] = f2b(a.x); tmp[1] = f2b(a.y); tmp[2] = f2b(a.z); tmp[3] = f2b(a.w);
            tmp[4] = f2b(b.x); tmp[5] = f2b(b.y); tmp[6] = f2b(b.z); tmp[7] = f2b(b.w);
        }
        afe = *(bf16x8*)tmp;
    }
    __syncthreads();   // (1) b1s ready

    // Phase A: g = relu(ea@We1+be1) via MFMA -> bf16 As[64][128]
#pragma unroll
    for (int nt = 0; nt < 8; ++nt) {
        bf16x8 bfe = *(const bf16x8*)(we1B + (size_t)((nt << 6) + l) * 8);
        int kh = nt * 16 + lr;
        float bb = b1s[kh];
        f32x4 acc = (f32x4){0.f, 0.f, 0.f, 0.f};
        acc = __builtin_amdgcn_mfma_f32_16x16x32_bf16(afe, bfe, acc, 0, 0, 0);
#pragma unroll
        for (int r = 0; r < 4; ++r)
            AsHs[(w * 16 + lg * 4 + r) * LDA + kh] = f2b(fmaxf(acc[r] + bb, 0.f));
    }
    __syncthreads();   // (2) As complete

    bf16x8 afrag[4];
#pragma unroll
    for (int kt = 0; kt < 4; ++kt)
        afrag[kt] = *(const bf16x8*)(&AsHs[(w * 16 + lr) * LDA + kt * 32 + lg * 8]);
    __syncthreads();   // (3) As reads done -> region becomes Hs + Bs

    // Gather h[src] into Hs (4 threads per edge row)
    {
        int row = t >> 2, qtr = t & 3;
        int e = e0 + row;
        float4* hd = (float4*)(Hs + row * HPAD) + qtr * 2;
        if (e < N_EDGES) {
            const float4* hr = (const float4*)(h + (size_t)ei[e] * DD) + qtr * 2;
            hd[0] = hr[0];
            hd[1] = hr[1];
        } else {
            float4 z = make_float4(0.f, 0.f, 0.f, 0.f);
            hd[0] = z; hd[1] = z;
        }
    }
    // Stage bn=0 weight tile: L2 -> LDS DMA, zero staging VGPRs.
#pragma unroll
    for (int q = 0; q < 4; ++q) {
        const ushort* gsrc = we2B + (size_t)(q * 256 + t) * 8;          // per-lane
        ushort* ldst = Bs + (size_t)(q * 256 + w * 64) * 8;             // wave-uniform
        __builtin_amdgcn_global_load_lds(
            (const __attribute__((address_space(1))) unsigned int*)gsrc,
            (__attribute__((address_space(3))) unsigned int*)ldst, 16, 0, 0);
    }
    asm volatile("s_waitcnt vmcnt(0)" ::: "memory");
    __syncthreads();   // (4) Hs + Bs(0) ready

    float m_acc[4][2];
#pragma unroll
    for (int r = 0; r < 4; ++r) { m_acc[r][0] = 0.f; m_acc[r][1] = 0.f; }

    for (int bn = 0; bn < 16; ++bn) {
        // Bias folded into accumulator init (C-in accumulates through MFMA)
        f32x4 acc[4];
#pragma unroll
        for (int nt = 0; nt < 4; ++nt) {
            float bv = be2s[bn * 64 + nt * 16 + lr];
            acc[nt] = (f32x4){bv, bv, bv, bv};
        }

#pragma unroll
        for (int kt = 0; kt < 4; ++kt) {
            const ushort* base = Bs + (size_t)(kt * 64 + l) * 8;
            bf16x8 b0 = *(const bf16x8*)(base);
            bf16x8 b1 = *(const bf16x8*)(base + 2048);
            bf16x8 b2 = *(const bf16x8*)(base + 4096);
            bf16x8 b3 = *(const bf16x8*)(base + 6144);
            acc[0] = __builtin_amdgcn_mfma_f32_16x16x32_bf16(afrag[kt], b0, acc[0], 0, 0, 0);
            acc[1] = __builtin_amdgcn_mfma_f32_16x16x32_bf16(afrag[kt], b1, acc[1], 0, 0, 0);
            acc[2] = __builtin_amdgcn_mfma_f32_16x16x32_bf16(afrag[kt], b2, acc[2], 0, 0, 0);
            acc[3] = __builtin_amdgcn_mfma_f32_16x16x32_bf16(afrag[kt], b3, acc[3], 0, 0, 0);
        }

        // Fold: col=bn*64+nt*16+lr -> i=2bn+(nt>>1), o=16*(nt&1)+lr
#pragma unroll
        for (int r = 0; r < 4; ++r) {
            int row = w * 16 + lg * 4 + r;
            float2 hv = *(const float2*)(Hs + row * HPAD + bn * 2);
#pragma unroll
            for (int nt = 0; nt < 4; ++nt) {
                float hi = (nt >> 1) ? hv.y : hv.x;
                m_acc[r][nt & 1] += hi * acc[nt][r];
            }
        }

        if (bn < 15) {
            __syncthreads();   // all waves done reading Bs(bn)
#pragma unroll
            for (int q = 0; q < 4; ++q) {
                const ushort* gsrc = we2B + (size_t)(bn + 1) * 8192 + (size_t)(q * 256 + t) * 8;
                ushort* ldst = Bs + (size_t)(q * 256 + w * 64) * 8;
                __builtin_amdgcn_global_load_lds(
                    (const __attribute__((address_space(1))) unsigned int*)gsrc,
                    (__attribute__((address_space(3))) unsigned int*)ldst, 16, 0, 0);
            }
            asm volatile("s_waitcnt vmcnt(0)" ::: "memory");
            __syncthreads();   // Bs(bn+1) ready
        }
    }

    // Scatter: agg[dst] += m (atomic; register-direct)
#pragma unroll
    for (int r = 0; r < 4; ++r) {
        int le = w * 16 + lg * 4 + r;
        int e = e0 + le;
        if (e < N_EDGES) {
            int dst = ei[N_EDGES + e];
            float* ar = agg + (size_t)dst * DD;
            atomicAdd(ar + lr,      m_acc[r][0]);
            atomicAdd(ar + lr + 16, m_acc[r][1]);
        }
    }
}

// ---------------------------------------------------------------------------
// conv_gru (R13 form, verified equal-perf): LDS-staged agg + vectorized h
// load; fast-exp GRU tail (R11/R12-verified numerics). agg aliases out:
// per-block agg region zeroed before barrier, out written after; blocks own
// disjoint rows.
__global__ __launch_bounds__(256) void conv_gru(float* agg,
                                                float* __restrict__ h,
                                                const ushort* __restrict__ wgB,
                                                const float* __restrict__ bconv,
                                                const float* __restrict__ bih,
                                                const float* __restrict__ bhh,
                                                float* out) {
    __shared__ __attribute__((aligned(16))) ushort Ah[64 * 40];   // 5120 B
    __shared__ __attribute__((aligned(16))) ushort Ac[64 * 40];   // 5120 B
    __shared__ float hs[64 * 33];                                 // 8448 B
    __shared__ __attribute__((aligned(16))) float ags[64 * DD];   // 8192 B
    __shared__ float bcs[DD], bis[3 * DD], bhs[3 * DD];
    int t = threadIdx.x;
    int base = blockIdx.x * 64;

    // Vectorized stage: 512 float4 cover [64 nodes][32 cols] of h and agg.
    {
        size_t fbase = (size_t)base * DD;          // float offset of block
        size_t ftotal = (size_t)N_NODES * DD;
#pragma unroll
        for (int it = 0; it < 2; ++it) {
            int i4 = t + it * 256;                 // [0,512)
            size_t fo = fbase + (size_t)i4 * 4;
            int row = i4 >> 3, q = i4 & 7;         // 8 float4 per 32-col row
            if (fo < ftotal) {
                float4 hv = *(const float4*)(h + fo);
                float4 av = *(const float4*)(agg + fo);
                *(float4*)(agg + fo) = make_float4(0.f, 0.f, 0.f, 0.f);
                *(float4*)(&ags[row * DD + q * 4]) = av;
                int c0 = q * 4;
                hs[row * 33 + c0]     = hv.x;
                hs[row * 33 + c0 + 1] = hv.y;
                hs[row * 33 + c0 + 2] = hv.z;
                hs[row * 33 + c0 + 3] = hv.w;
                Ah[row * 40 + c0]     = f2b(hv.x);
                Ah[row * 40 + c0 + 1] = f2b(hv.y);
                Ah[row * 40 + c0 + 2] = f2b(hv.z);
                Ah[row * 40 + c0 + 3] = f2b(hv.w);
            } else {
                *(float4*)(&ags[row * DD + q * 4]) = make_float4(0.f, 0.f, 0.f, 0.f);
                int c0 = q * 4;
                hs[row * 33 + c0]     = 0.f;
                hs[row * 33 + c0 + 1] = 0.f;
                hs[row * 33 + c0 + 2] = 0.f;
                hs[row * 33 + c0 + 3] = 0.f;
                Ah[row * 40 + c0]     = 0;
                Ah[row * 40 + c0 + 1] = 0;
                Ah[row * 40 + c0 + 2] = 0;
                Ah[row * 40 + c0 + 3] = 0;
            }
        }
    }
    if (t < DD) bcs[t] = bconv[t];
    if (t < 3 * DD) { bis[t] = bih[t]; bhs[t] = bhh[t]; }
    __syncthreads();

    int w = t >> 6, l = t & 63;
    int lr = l & 15, lg = l >> 4;
    const f32x4 zro = (f32x4){0.f, 0.f, 0.f, 0.f};

    bf16x8 ah = *(const bf16x8*)(&Ah[(w * 16 + lr) * 40 + lg * 8]);

    // conv GEMM (2 n-tiles, K=32)
    f32x4 dcv[2];
#pragma unroll
    for (int nt = 0; nt < 2; ++nt) {
        bf16x8 b = *(const bf16x8*)(wgB + (size_t)(nt * 64 + l) * 8);
        dcv[nt] = __builtin_amdgcn_mfma_f32_16x16x32_bf16(ah, b, zro, 0, 0, 0);
    }
    // epilogue: + ags(LDS) + bc, relu -> bf16 Ac
#pragma unroll
    for (int nt = 0; nt < 2; ++nt) {
#pragma unroll
        for (int r = 0; r < 4; ++r) {
            int row = w * 16 + lg * 4 + r;
            int col = nt * 16 + lr;
            float a = ags[row * DD + col];
            Ac[row * 40 + col] = f2b(fmaxf(dcv[nt][r] + a + bcs[col], 0.f));
        }
    }
    __syncthreads();

    bf16x8 ac = *(const bf16x8*)(&Ac[(w * 16 + lr) * 40 + lg * 8]);

    // gate GEMMs: gi = conv@Wih^T (+bi), gh = h@Whh^T (+bh); 6 n-tiles each
    f32x4 gi[6], gh[6];
#pragma unroll
    for (int nt = 0; nt < 6; ++nt) {
        bf16x8 bi_ = *(const bf16x8*)(wgB + (size_t)(128 + nt * 64 + l) * 8);
        gi[nt] = __builtin_amdgcn_mfma_f32_16x16x32_bf16(ac, bi_, zro, 0, 0, 0);
        bf16x8 bh_ = *(const bf16x8*)(wgB + (size_t)(512 + nt * 64 + l) * 8);
        gh[nt] = __builtin_amdgcn_mfma_f32_16x16x32_bf16(ah, bh_, zro, 0, 0, 0);
    }

    // elementwise GRU (fast-exp, R11/R12-verified numerics)
#pragma unroll
    for (int r = 0; r < 4; ++r) {
        int row = w * 16 + lg * 4 + r;
        int n = base + row;
        if (n >= N_NODES) continue;
#pragma unroll
        for (int ch = 0; ch < 2; ++ch) {
            int o = ch * 16 + lr;
            float girv = gi[ch][r]     + bis[o];
            float gizv = gi[2 + ch][r] + bis[DD + o];
            float ginv = gi[4 + ch][r] + bis[2 * DD + o];
            float ghrv = gh[ch][r]     + bhs[o];
            float ghzv = gh[2 + ch][r] + bhs[DD + o];
            float ghnv = gh[4 + ch][r] + bhs[2 * DD + o];
            float R  = 1.f / (1.f + __expf(-(girv + ghrv)));
            float Z  = 1.f / (1.f + __expf(-(gizv + ghzv)));
            float xa = ginv + R * ghnv;
            float e2 = __expf(2.f * xa);
            float Nn = 1.f - 2.f / (e2 + 1.f);
            float hold = hs[row * 33 + o];
            float hnew = (1.f - Z) * Nn + Z * hold;
            h[(size_t)n * DD + o] = hnew;
            if (out) out[(size_t)n * DD + o] = hnew;
        }
    }
}

// ---------------------------------------------------------------------------
extern "C" void kernel_launch(void* const* d_in, const int* in_sizes, int n_in,
                              void* d_out, int out_size, void* d_ws, size_t ws_size,
                              hipStream_t stream) {
    const float* x    = (const float*)d_in[0];
    const int*   ei   = (const int*)d_in[1];
    const float* ea   = (const float*)d_in[2];
    const float* Wn   = (const float*)d_in[3];
    const float* bn   = (const float*)d_in[4];
    const float* We1  = (const float*)d_in[5];
    const float* be1  = (const float*)d_in[6];
    const float* We2  = (const float*)d_in[7];
    const float* be2  = (const float*)d_in[8];
    const float* Wroot= (const float*)d_in[9];
    const float* bconv= (const float*)d_in[10];
    const float* Wih  = (const float*)d_in[11];
    const float* Whh  = (const float*)d_in[12];
    const float* bih  = (const float*)d_in[13];
    const float* bhh  = (const float*)d_in[14];
    float* out = (float*)d_out;   // fp32 output

    // ---- Workspace: 6.68 MB (R10 layout; agg aliases d_out) ----
    char* ws = (char*)d_ws;
    float*  h    = (float*)(ws);                    // 6,400,000
    ushort* we2B = (ushort*)(ws + 6400000);         //   262,144 fragment-major We2T
    ushort* we1B = (ushort*)(ws + 6662144);         //     8,192 fragment-major We1T
    ushort* wgB  = (ushort*)(ws + 6670336);         //    14,336 fragment-major GRU weights
    float*  agg  = (float*)d_out;                   // aliases output buffer

    // setup covers prep + node_init + agg zeroing (364 blocks, 1 dispatch)
    setup<<<364, 256, 0, stream>>>(We2, We1, Wroot, Wih, Whh, we2B, we1B, wgB,
                                   x, Wn, bn, h, agg);

    for (int step = 0; step < STEPS; ++step) {
        fused_msg<<<(N_EDGES + EPB - 1) / EPB, 256, 0, stream>>>(ea, we1B, be1, we2B, be2,
                                                                 ei, h, agg);
        conv_gru<<<(N_NODES + 63) / 64, 256, 0, stream>>>(agg, h, wgB, bconv, bih, bhh,
                                                          (step == STEPS - 1) ? out : nullptr);
    }
}

// Round 15
// 304.108 us; speedup vs baseline: 8.2298x; 8.2298x over previous
//
#include <hip/hip_runtime.h>
#include <hip/hip_bf16.h>

// Problem constants (from reference)
#define N_NODES 50000
#define N_EDGES 150000
#define NODE_IN 64
#define EDGE_IN 16
#define DD 32          // node feature dim
#define EHID 128       // edge-network hidden
#define STEPS 3
#define EPB 64         // edges per fused_msg block: LDS 30208B -> 5 blocks/CU

// Device-verified harness dtypes: float inputs fp32, edge_index int32, output fp32.
__device__ __forceinline__ ushort f2b(float f) {
    __hip_bfloat16 b = __float2bfloat16(f);   // RNE
    return *reinterpret_cast<ushort*>(&b);
}

typedef __bf16 bf16x8 __attribute__((ext_vector_type(8)));
typedef float  f32x4  __attribute__((ext_vector_type(4)));

#define LDA  136   // As leading dim (ushorts)
#define HPAD 36    // Hs leading dim (floats)

// ---------------------------------------------------------------------------
// setup (R12-proven): merged prep + node_init + agg-zero.
// blocks [0,70): weight repack; [70,266): node_init; [266,364): zero agg.
__global__ __launch_bounds__(256) void setup(const float* __restrict__ we2,
                                             const float* __restrict__ we1,
                                             const float* __restrict__ wroot,
                                             const float* __restrict__ wih,
                                             const float* __restrict__ whh,
                                             ushort* __restrict__ we2B,
                                             ushort* __restrict__ we1B,
                                             ushort* __restrict__ wgB,
                                             const float* __restrict__ x,
                                             const float* __restrict__ Wn,
                                             const float* __restrict__ bn,
                                             float* __restrict__ h,
                                             float* __restrict__ agg) {
    __shared__ float Wns[NODE_IN * DD];   // node_init blocks only
    __shared__ float bns[DD];
    int b = blockIdx.x, t = threadIdx.x;

    if (b < 70) {   // ---- prep (R4-proven 16x16 fragment layout) ----
        int i = b * 256 + t;
        if (i < 16384) {
            int l = i & 63, f = i >> 6;           // f = bn*16 + nt*4 + kt
            int kt = f & 3, nt = (f >> 2) & 3, bq = f >> 4;
            int lr = l & 15, lg = l >> 4;
            int n = bq * 64 + nt * 16 + lr;
            int k0 = kt * 32 + lg * 8;
            ushort tmp[8];
#pragma unroll
            for (int j = 0; j < 8; ++j) tmp[j] = f2b(we2[(size_t)(k0 + j) * 1024 + n]);
            *(uint4*)(we2B + (size_t)i * 8) = *(uint4*)tmp;
        } else if (i < 16896) {
            int u = i - 16384;
            int l = u & 63, nt = u >> 6;
            int lr = l & 15, lg = l >> 4;
            int n = nt * 16 + lr;
            ushort tmp[8];
#pragma unroll
            for (int j = 0; j < 8; ++j) {
                int k = lg * 8 + j;
                tmp[j] = (k < EDGE_IN) ? f2b(we1[(size_t)k * EHID + n]) : (ushort)0;
            }
            *(uint4*)(we1B + (size_t)u * 8) = *(uint4*)tmp;
        } else if (i < 17792) {
            int u = i - 16896;
            int l = u & 63;
            int lr = l & 15, lg = l >> 4;
            ushort tmp[8];
            if (u < 128) {            // Wroot [i][o] row-major
                int nt = u >> 6;
#pragma unroll
                for (int j = 0; j < 8; ++j)
                    tmp[j] = f2b(wroot[(size_t)(lg * 8 + j) * DD + nt * 16 + lr]);
            } else if (u < 512) {     // Wih
                int nt = (u - 128) >> 6;
#pragma unroll
                for (int j = 0; j < 8; ++j)
                    tmp[j] = f2b(wih[(size_t)(nt * 16 + lr) * DD + lg * 8 + j]);
            } else {                  // Whh
                int nt = (u - 512) >> 6;
#pragma unroll
                for (int j = 0; j < 8; ++j)
                    tmp[j] = f2b(whh[(size_t)(nt * 16 + lr) * DD + lg * 8 + j]);
            }
            *(uint4*)(wgB + (size_t)u * 8) = *(uint4*)tmp;
        }
    } else if (b < 266) {   // ---- node_init ----
        for (int i = t; i < NODE_IN * DD; i += 256) Wns[i] = Wn[i];
        if (t < DD) bns[t] = bn[t];
        __syncthreads();
        int n = (b - 70) * 256 + t;
        if (n >= N_NODES) return;
        float xr[NODE_IN];
        const float4* xp = (const float4*)(x + (size_t)n * NODE_IN);
#pragma unroll
        for (int q = 0; q < NODE_IN / 4; ++q) *(float4*)&xr[q * 4] = xp[q];
        float out[DD];
#pragma unroll
        for (int o = 0; o < DD; ++o) {
            float s = bns[o];
#pragma unroll
            for (int i = 0; i < NODE_IN; ++i) s += xr[i] * Wns[i * DD + o];
            out[o] = fmaxf(s, 0.f);
        }
        float4* hp = (float4*)(h + (size_t)n * DD);
#pragma unroll
        for (int q = 0; q < DD / 4; ++q) hp[q] = *(float4*)&out[q * 4];
    } else {   // ---- zero agg: blocks [266,364), 16 float4 per thread ----
        size_t total = (size_t)N_NODES * DD;        // 1.6M floats
        size_t base = ((size_t)(b - 266) * 256 + t) * 64;
        float4 z = make_float4(0.f, 0.f, 0.f, 0.f);
#pragma unroll
        for (int q = 0; q < 16; ++q) {
            size_t idx = base + (size_t)q * 4;
            if (idx < total) *(float4*)(agg + idx) = z;
        }
    }
}

// ---------------------------------------------------------------------------
// fused_msg (R10/R13-proven, zero-init accumulators — NOTE: acc MUST be
// zero-initialized; R14's bias-in-acc init caused scratch spill, 800+ µs):
// 16x16 MFMA, LDS-staged we2B via global_load_lds, direct ei indexing,
// atomic scatter; EPB=64 -> 5 blocks/CU.
__global__ __launch_bounds__(256, 5) void fused_msg(const float* __restrict__ ea,
                                                    const ushort* __restrict__ we1B,
                                                    const float* __restrict__ be1,
                                                    const ushort* __restrict__ we2B,
                                                    const float* __restrict__ be2,
                                                    const int* __restrict__ ei,
                                                    const float* __restrict__ h,
                                                    float* __restrict__ agg) {
    // region = max(As 64x136x2 = 17408B, Hs 9216B + Bs 16384B = 25600B)
    __shared__ __attribute__((aligned(16))) ushort AsHs[12800];      // 25600 B
    __shared__ float b1s[EHID];                                      // 512 B
    __shared__ float be2s[DD * DD];                                  // 4096 B
    float* Hs = (float*)AsHs;            // [64][HPAD] fp32 view (phase B)
    ushort* Bs = AsHs + 4608;            // bytes [9216, 25600): bn weight tile

    int t = threadIdx.x;
    if (t < EHID) b1s[t] = be1[t];
    for (int i = t; i < DD * DD; i += 256) be2s[i] = be2[i];

    int w = t >> 6, l = t & 63;
    int lr = l & 15, lg = l >> 4;
    int e0 = blockIdx.x * EPB;

    // Phase A input fragment straight from global (direct, coalesced)
    bf16x8 afe;
    {
        int e = e0 + w * 16 + lr;
        ushort tmp[8] = {0, 0, 0, 0, 0, 0, 0, 0};
        if (lg < 2 && e < N_EDGES) {
            const float4* p = (const float4*)(ea + (size_t)e * EDGE_IN + lg * 8);
            float4 a = p[0], b = p[1];
            tmp[0] = f2b(a.x); tmp[1] = f2b(a.y); tmp[2] = f2b(a.z); tmp[3] = f2b(a.w);
            tmp[4] = f2b(b.x); tmp[5] = f2b(b.y); tmp[6] = f2b(b.z); tmp[7] = f2b(b.w);
        }
        afe = *(bf16x8*)tmp;
    }
    __syncthreads();   // (1) b1s ready

    // Phase A: g = relu(ea@We1+be1) via MFMA -> bf16 As[64][128]
#pragma unroll
    for (int nt = 0; nt < 8; ++nt) {
        bf16x8 bfe = *(const bf16x8*)(we1B + (size_t)((nt << 6) + l) * 8);
        int kh = nt * 16 + lr;
        float bb = b1s[kh];
        f32x4 acc = (f32x4){0.f, 0.f, 0.f, 0.f};
        acc = __builtin_amdgcn_mfma_f32_16x16x32_bf16(afe, bfe, acc, 0, 0, 0);
#pragma unroll
        for (int r = 0; r < 4; ++r)
            AsHs[(w * 16 + lg * 4 + r) * LDA + kh] = f2b(fmaxf(acc[r] + bb, 0.f));
    }
    __syncthreads();   // (2) As complete

    bf16x8 afrag[4];
#pragma unroll
    for (int kt = 0; kt < 4; ++kt)
        afrag[kt] = *(const bf16x8*)(&AsHs[(w * 16 + lr) * LDA + kt * 32 + lg * 8]);
    __syncthreads();   // (3) As reads done -> region becomes Hs + Bs

    // Gather h[src] into Hs (4 threads per edge row)
    {
        int row = t >> 2, qtr = t & 3;
        int e = e0 + row;
        float4* hd = (float4*)(Hs + row * HPAD) + qtr * 2;
        if (e < N_EDGES) {
            const float4* hr = (const float4*)(h + (size_t)ei[e] * DD) + qtr * 2;
            hd[0] = hr[0];
            hd[1] = hr[1];
        } else {
            float4 z = make_float4(0.f, 0.f, 0.f, 0.f);
            hd[0] = z; hd[1] = z;
        }
    }
    // Stage bn=0 weight tile: L2 -> LDS DMA, zero staging VGPRs.
#pragma unroll
    for (int q = 0; q < 4; ++q) {
        const ushort* gsrc = we2B + (size_t)(q * 256 + t) * 8;          // per-lane
        ushort* ldst = Bs + (size_t)(q * 256 + w * 64) * 8;             // wave-uniform
        __builtin_amdgcn_global_load_lds(
            (const __attribute__((address_space(1))) unsigned int*)gsrc,
            (__attribute__((address_space(3))) unsigned int*)ldst, 16, 0, 0);
    }
    asm volatile("s_waitcnt vmcnt(0)" ::: "memory");
    __syncthreads();   // (4) Hs + Bs(0) ready

    float m_acc[4][2];
#pragma unroll
    for (int r = 0; r < 4; ++r) { m_acc[r][0] = 0.f; m_acc[r][1] = 0.f; }

    for (int bn = 0; bn < 16; ++bn) {
        float bv[4];
#pragma unroll
        for (int nt = 0; nt < 4; ++nt) bv[nt] = be2s[bn * 64 + nt * 16 + lr];

        f32x4 acc[4];
#pragma unroll
        for (int nt = 0; nt < 4; ++nt) acc[nt] = (f32x4){0.f, 0.f, 0.f, 0.f};

#pragma unroll
        for (int kt = 0; kt < 4; ++kt) {
            const ushort* base = Bs + (size_t)(kt * 64 + l) * 8;
            bf16x8 b0 = *(const bf16x8*)(base);
            bf16x8 b1 = *(const bf16x8*)(base + 2048);
            bf16x8 b2 = *(const bf16x8*)(base + 4096);
            bf16x8 b3 = *(const bf16x8*)(base + 6144);
            acc[0] = __builtin_amdgcn_mfma_f32_16x16x32_bf16(afrag[kt], b0, acc[0], 0, 0, 0);
            acc[1] = __builtin_amdgcn_mfma_f32_16x16x32_bf16(afrag[kt], b1, acc[1], 0, 0, 0);
            acc[2] = __builtin_amdgcn_mfma_f32_16x16x32_bf16(afrag[kt], b2, acc[2], 0, 0, 0);
            acc[3] = __builtin_amdgcn_mfma_f32_16x16x32_bf16(afrag[kt], b3, acc[3], 0, 0, 0);
        }

        // Fold: col=bn*64+nt*16+lr -> i=2bn+(nt>>1), o=16*(nt&1)+lr
#pragma unroll
        for (int r = 0; r < 4; ++r) {
            int row = w * 16 + lg * 4 + r;
            float2 hv = *(const float2*)(Hs + row * HPAD + bn * 2);
#pragma unroll
            for (int nt = 0; nt < 4; ++nt) {
                float hi = (nt >> 1) ? hv.y : hv.x;
                m_acc[r][nt & 1] += hi * (acc[nt][r] + bv[nt]);
            }
        }

        if (bn < 15) {
            __syncthreads();   // all waves done reading Bs(bn)
#pragma unroll
            for (int q = 0; q < 4; ++q) {
                const ushort* gsrc = we2B + (size_t)(bn + 1) * 8192 + (size_t)(q * 256 + t) * 8;
                ushort* ldst = Bs + (size_t)(q * 256 + w * 64) * 8;
                __builtin_amdgcn_global_load_lds(
                    (const __attribute__((address_space(1))) unsigned int*)gsrc,
                    (__attribute__((address_space(3))) unsigned int*)ldst, 16, 0, 0);
            }
            asm volatile("s_waitcnt vmcnt(0)" ::: "memory");
            __syncthreads();   // Bs(bn+1) ready
        }
    }

    // Scatter: agg[dst] += m (atomic; register-direct)
#pragma unroll
    for (int r = 0; r < 4; ++r) {
        int le = w * 16 + lg * 4 + r;
        int e = e0 + le;
        if (e < N_EDGES) {
            int dst = ei[N_EDGES + e];
            float* ar = agg + (size_t)dst * DD;
            atomicAdd(ar + lr,      m_acc[r][0]);
            atomicAdd(ar + lr + 16, m_acc[r][1]);
        }
    }
}

// ---------------------------------------------------------------------------
// conv_gru (R13 form): LDS-staged agg + vectorized h load; fast-exp GRU tail
// (R11/R12-verified numerics). agg aliases out: per-block agg region zeroed
// before barrier, out written after; blocks own disjoint rows.
__global__ __launch_bounds__(256) void conv_gru(float* agg,
                                                float* __restrict__ h,
                                                const ushort* __restrict__ wgB,
                                                const float* __restrict__ bconv,
                                                const float* __restrict__ bih,
                                                const float* __restrict__ bhh,
                                                float* out) {
    __shared__ __attribute__((aligned(16))) ushort Ah[64 * 40];   // 5120 B
    __shared__ __attribute__((aligned(16))) ushort Ac[64 * 40];   // 5120 B
    __shared__ float hs[64 * 33];                                 // 8448 B
    __shared__ __attribute__((aligned(16))) float ags[64 * DD];   // 8192 B
    __shared__ float bcs[DD], bis[3 * DD], bhs[3 * DD];
    int t = threadIdx.x;
    int base = blockIdx.x * 64;

    // Vectorized stage: 512 float4 cover [64 nodes][32 cols] of h and agg.
    {
        size_t fbase = (size_t)base * DD;          // float offset of block
        size_t ftotal = (size_t)N_NODES * DD;
#pragma unroll
        for (int it = 0; it < 2; ++it) {
            int i4 = t + it * 256;                 // [0,512)
            size_t fo = fbase + (size_t)i4 * 4;
            int row = i4 >> 3, q = i4 & 7;         // 8 float4 per 32-col row
            if (fo < ftotal) {
                float4 hv = *(const float4*)(h + fo);
                float4 av = *(const float4*)(agg + fo);
                *(float4*)(agg + fo) = make_float4(0.f, 0.f, 0.f, 0.f);
                *(float4*)(&ags[row * DD + q * 4]) = av;
                int c0 = q * 4;
                hs[row * 33 + c0]     = hv.x;
                hs[row * 33 + c0 + 1] = hv.y;
                hs[row * 33 + c0 + 2] = hv.z;
                hs[row * 33 + c0 + 3] = hv.w;
                Ah[row * 40 + c0]     = f2b(hv.x);
                Ah[row * 40 + c0 + 1] = f2b(hv.y);
                Ah[row * 40 + c0 + 2] = f2b(hv.z);
                Ah[row * 40 + c0 + 3] = f2b(hv.w);
            } else {
                *(float4*)(&ags[row * DD + q * 4]) = make_float4(0.f, 0.f, 0.f, 0.f);
                int c0 = q * 4;
                hs[row * 33 + c0]     = 0.f;
                hs[row * 33 + c0 + 1] = 0.f;
                hs[row * 33 + c0 + 2] = 0.f;
                hs[row * 33 + c0 + 3] = 0.f;
                Ah[row * 40 + c0]     = 0;
                Ah[row * 40 + c0 + 1] = 0;
                Ah[row * 40 + c0 + 2] = 0;
                Ah[row * 40 + c0 + 3] = 0;
            }
        }
    }
    if (t < DD) bcs[t] = bconv[t];
    if (t < 3 * DD) { bis[t] = bih[t]; bhs[t] = bhh[t]; }
    __syncthreads();

    int w = t >> 6, l = t & 63;
    int lr = l & 15, lg = l >> 4;
    const f32x4 zro = (f32x4){0.f, 0.f, 0.f, 0.f};

    bf16x8 ah = *(const bf16x8*)(&Ah[(w * 16 + lr) * 40 + lg * 8]);

    // conv GEMM (2 n-tiles, K=32)
    f32x4 dcv[2];
#pragma unroll
    for (int nt = 0; nt < 2; ++nt) {
        bf16x8 b = *(const bf16x8*)(wgB + (size_t)(nt * 64 + l) * 8);
        dcv[nt] = __builtin_amdgcn_mfma_f32_16x16x32_bf16(ah, b, zro, 0, 0, 0);
    }
    // epilogue: + ags(LDS) + bc, relu -> bf16 Ac
#pragma unroll
    for (int nt = 0; nt < 2; ++nt) {
#pragma unroll
        for (int r = 0; r < 4; ++r) {
            int row = w * 16 + lg * 4 + r;
            int col = nt * 16 + lr;
            float a = ags[row * DD + col];
            Ac[row * 40 + col] = f2b(fmaxf(dcv[nt][r] + a + bcs[col], 0.f));
        }
    }
    __syncthreads();

    bf16x8 ac = *(const bf16x8*)(&Ac[(w * 16 + lr) * 40 + lg * 8]);

    // gate GEMMs: gi = conv@Wih^T (+bi), gh = h@Whh^T (+bh); 6 n-tiles each
    f32x4 gi[6], gh[6];
#pragma unroll
    for (int nt = 0; nt < 6; ++nt) {
        bf16x8 bi_ = *(const bf16x8*)(wgB + (size_t)(128 + nt * 64 + l) * 8);
        gi[nt] = __builtin_amdgcn_mfma_f32_16x16x32_bf16(ac, bi_, zro, 0, 0, 0);
        bf16x8 bh_ = *(const bf16x8*)(wgB + (size_t)(512 + nt * 64 + l) * 8);
        gh[nt] = __builtin_amdgcn_mfma_f32_16x16x32_bf16(ah, bh_, zro, 0, 0, 0);
    }

    // elementwise GRU (fast-exp, R11/R12-verified numerics)
#pragma unroll
    for (int r = 0; r < 4; ++r) {
        int row = w * 16 + lg * 4 + r;
        int n = base + row;
        if (n >= N_NODES) continue;
#pragma unroll
        for (int ch = 0; ch < 2; ++ch) {
            int o = ch * 16 + lr;
            float girv = gi[ch][r]     + bis[o];
            float gizv = gi[2 + ch][r] + bis[DD + o];
            float ginv = gi[4 + ch][r] + bis[2 * DD + o];
            float ghrv = gh[ch][r]     + bhs[o];
            float ghzv = gh[2 + ch][r] + bhs[DD + o];
            float ghnv = gh[4 + ch][r] + bhs[2 * DD + o];
            float R  = 1.f / (1.f + __expf(-(girv + ghrv)));
            float Z  = 1.f / (1.f + __expf(-(gizv + ghzv)));
            float xa = ginv + R * ghnv;
            float e2 = __expf(2.f * xa);
            float Nn = 1.f - 2.f / (e2 + 1.f);
            float hold = hs[row * 33 + o];
            float hnew = (1.f - Z) * Nn + Z * hold;
            h[(size_t)n * DD + o] = hnew;
            if (out) out[(size_t)n * DD + o] = hnew;
        }
    }
}

// ---------------------------------------------------------------------------
extern "C" void kernel_launch(void* const* d_in, const int* in_sizes, int n_in,
                              void* d_out, int out_size, void* d_ws, size_t ws_size,
                              hipStream_t stream) {
    const float* x    = (const float*)d_in[0];
    const int*   ei   = (const int*)d_in[1];
    const float* ea   = (const float*)d_in[2];
    const float* Wn   = (const float*)d_in[3];
    const float* bn   = (const float*)d_in[4];
    const float* We1  = (const float*)d_in[5];
    const float* be1  = (const float*)d_in[6];
    const float* We2  = (const float*)d_in[7];
    const float* be2  = (const float*)d_in[8];
    const float* Wroot= (const float*)d_in[9];
    const float* bconv= (const float*)d_in[10];
    const float* Wih  = (const float*)d_in[11];
    const float* Whh  = (const float*)d_in[12];
    const float* bih  = (const float*)d_in[13];
    const float* bhh  = (const float*)d_in[14];
    float* out = (float*)d_out;   // fp32 output

    // ---- Workspace: 6.68 MB (R10 layout; agg aliases d_out) ----
    char* ws = (char*)d_ws;
    float*  h    = (float*)(ws);                    // 6,400,000
    ushort* we2B = (ushort*)(ws + 6400000);         //   262,144 fragment-major We2T
    ushort* we1B = (ushort*)(ws + 6662144);         //     8,192 fragment-major We1T
    ushort* wgB  = (ushort*)(ws + 6670336);         //    14,336 fragment-major GRU weights
    float*  agg  = (float*)d_out;                   // aliases output buffer

    // setup covers prep + node_init + agg zeroing (364 blocks, 1 dispatch)
    setup<<<364, 256, 0, stream>>>(We2, We1, Wroot, Wih, Whh, we2B, we1B, wgB,
                                   x, Wn, bn, h, agg);

    for (int step = 0; step < STEPS; ++step) {
        fused_msg<<<(N_EDGES + EPB - 1) / EPB, 256, 0, stream>>>(ea, we1B, be1, we2B, be2,
                                                                 ei, h, agg);
        conv_gru<<<(N_NODES + 63) / 64, 256, 0, stream>>>(agg, h, wgB, bconv, bih, bhh,
                                                          (step == STEPS - 1) ? out : nullptr);
    }
}